// Round 1
// baseline (681.238 us; speedup 1.0000x reference)
//
#include <hip/hip_runtime.h>
#include <hip/hip_bf16.h>
#include <stdint.h>

// RandLinear: out[n,o] = sum_i x[n,i] * (mu_w[o,i] + exp(ls_w[o,i])*eps_w[o,i]) + bias[o]
// Strategy: materialize W and x in bf16 (threshold 0.4075 admits bf16 MFMA),
// then m97-style bf16 GEMM-BT (128x128x32 tile, global_load_lds width=16).

constexpr int M    = 8192;  // rows of x ("N" in reference)
constexpr int K    = 4096;  // IN
constexpr int NOUT = 4096;  // OUT

typedef __bf16 bf16x8 __attribute__((ext_vector_type(8)));
typedef float  f32x4  __attribute__((ext_vector_type(4)));
typedef short  short8 __attribute__((ext_vector_type(8)));

#define DI __device__ __forceinline__

DI void gl_lds16(const void* g, void* l) {
  __builtin_amdgcn_global_load_lds(
      (__attribute__((address_space(1))) void*)(g),
      (__attribute__((address_space(3))) void*)(l),
      16, 0, 0);
}

union BF8 {
  __hip_bfloat16 h[8];
  short8 s;
};

// ---- cast x (fp32 -> bf16), 8 elems/thread ----
__global__ __launch_bounds__(256) void cast_x_kernel(const float* __restrict__ x,
                                                     short* __restrict__ xb) {
  int i = blockIdx.x * 256 + threadIdx.x;  // chunk of 8 floats
  const float4* src = (const float4*)x;
  float4 f0 = src[2 * i + 0];
  float4 f1 = src[2 * i + 1];
  BF8 u;
  u.h[0] = __float2bfloat16(f0.x);
  u.h[1] = __float2bfloat16(f0.y);
  u.h[2] = __float2bfloat16(f0.z);
  u.h[3] = __float2bfloat16(f0.w);
  u.h[4] = __float2bfloat16(f1.x);
  u.h[5] = __float2bfloat16(f1.y);
  u.h[6] = __float2bfloat16(f1.z);
  u.h[7] = __float2bfloat16(f1.w);
  ((short8*)xb)[i] = u.s;
}

// ---- W = mu + exp(ls)*eps, cast to bf16, 8 elems/thread ----
__global__ __launch_bounds__(256) void w_fuse_kernel(const float* __restrict__ mu,
                                                     const float* __restrict__ ls,
                                                     const float* __restrict__ eps,
                                                     short* __restrict__ wb) {
  int i = blockIdx.x * 256 + threadIdx.x;
  const float4* mu4 = (const float4*)mu;
  const float4* ls4 = (const float4*)ls;
  const float4* ep4 = (const float4*)eps;
  float4 m0 = mu4[2 * i + 0], m1 = mu4[2 * i + 1];
  float4 l0 = ls4[2 * i + 0], l1 = ls4[2 * i + 1];
  float4 e0 = ep4[2 * i + 0], e1 = ep4[2 * i + 1];
  BF8 u;
  u.h[0] = __float2bfloat16(m0.x + __expf(l0.x) * e0.x);
  u.h[1] = __float2bfloat16(m0.y + __expf(l0.y) * e0.y);
  u.h[2] = __float2bfloat16(m0.z + __expf(l0.z) * e0.z);
  u.h[3] = __float2bfloat16(m0.w + __expf(l0.w) * e0.w);
  u.h[4] = __float2bfloat16(m1.x + __expf(l1.x) * e1.x);
  u.h[5] = __float2bfloat16(m1.y + __expf(l1.y) * e1.y);
  u.h[6] = __float2bfloat16(m1.z + __expf(l1.z) * e1.z);
  u.h[7] = __float2bfloat16(m1.w + __expf(l1.w) * e1.w);
  ((short8*)wb)[i] = u.s;
}

// ---- bias = mu_b + exp(ls_b)*eps_b (fp32) ----
__global__ __launch_bounds__(256) void bias_kernel(const float* __restrict__ mu_b,
                                                   const float* __restrict__ ls_b,
                                                   const float* __restrict__ eps_b,
                                                   float* __restrict__ bias) {
  int i = blockIdx.x * 256 + threadIdx.x;
  if (i < NOUT) bias[i] = mu_b[i] + expf(ls_b[i]) * eps_b[i];
}

// ---- GEMM: C[m,n] = sum_k A[m,k]*B[n,k] + bias[n]   (A:[M,K] bf16, B:[N,K] bf16) ----
__global__ __launch_bounds__(256) void gemm_bt_kernel(const short* __restrict__ A,
                                                      const short* __restrict__ B,
                                                      const float* __restrict__ bias,
                                                      float* __restrict__ C) {
  constexpr int BM = 128, BN = 128, BK = 32;
  __shared__ short As[BM * BK];  // 8 KB, lane-order contiguous (global_load_lds)
  __shared__ short Bs[BN * BK];  // 8 KB

  const int tid  = threadIdx.x;
  const int lane = tid & 63;
  const int wave = tid >> 6;
  const int wm   = wave >> 1;    // 0..1: which 64-row half
  const int wn   = wave & 1;     // 0..1: which 64-col half
  const int m0   = blockIdx.y * BM;
  const int n0   = blockIdx.x * BN;
  const int mrow = lane & 15;
  const int quad = lane >> 4;

  f32x4 acc[4][4] = {};

  for (int k0 = 0; k0 < K; k0 += BK) {
    // Stage A and B tiles: each tile = 512 chunks of 16B; 256 threads x 2 iters.
    // LDS chunk c (row = c>>2, q = c&3) holds global k-span [k0+q*8, +8) of tile row.
#pragma unroll
    for (int it = 0; it < 2; ++it) {
      int cb  = it * 256 + wave * 64;  // wave-uniform chunk base
      int c   = cb + lane;
      int row = c >> 2;
      int q   = c & 3;
      gl_lds16(A + (size_t)(m0 + row) * K + k0 + q * 8, (char*)As + cb * 16);
      gl_lds16(B + (size_t)(n0 + row) * K + k0 + q * 8, (char*)Bs + cb * 16);
    }
    __syncthreads();

    bf16x8 a[4], b[4];
#pragma unroll
    for (int mi = 0; mi < 4; ++mi)
      a[mi] = *(const bf16x8*)&As[(wm * 64 + mi * 16 + mrow) * BK + quad * 8];
#pragma unroll
    for (int ni = 0; ni < 4; ++ni)
      b[ni] = *(const bf16x8*)&Bs[(wn * 64 + ni * 16 + mrow) * BK + quad * 8];

#pragma unroll
    for (int mi = 0; mi < 4; ++mi)
#pragma unroll
      for (int ni = 0; ni < 4; ++ni)
        acc[mi][ni] = __builtin_amdgcn_mfma_f32_16x16x32_bf16(a[mi], b[ni], acc[mi][ni], 0, 0, 0);

    __syncthreads();
  }

  // Epilogue: C/D layout col = lane&15, row = quad*4 + reg.
#pragma unroll
  for (int ni = 0; ni < 4; ++ni) {
    int col  = n0 + wn * 64 + ni * 16 + mrow;
    float bv = bias[col];
#pragma unroll
    for (int mi = 0; mi < 4; ++mi) {
      int rowb = m0 + wm * 64 + mi * 16 + quad * 4;
#pragma unroll
      for (int r = 0; r < 4; ++r)
        C[(size_t)(rowb + r) * NOUT + col] = acc[mi][ni][r] + bv;
    }
  }
}

extern "C" void kernel_launch(void* const* d_in, const int* in_sizes, int n_in,
                              void* d_out, int out_size, void* d_ws, size_t ws_size,
                              hipStream_t stream) {
  const float* x    = (const float*)d_in[0];
  const float* mu_w = (const float*)d_in[1];
  const float* ls_w = (const float*)d_in[2];
  const float* mu_b = (const float*)d_in[3];
  const float* ls_b = (const float*)d_in[4];
  const float* ep_w = (const float*)d_in[5];
  const float* ep_b = (const float*)d_in[6];
  float* out = (float*)d_out;

  // Workspace layout
  char* ws = (char*)d_ws;
  short* xb   = (short*)(ws);                                  // M*K bf16   = 64 MiB
  short* wb   = (short*)(ws + (size_t)M * K * 2);              // NOUT*K bf16= 32 MiB
  float* bias = (float*)(ws + (size_t)M * K * 2 + (size_t)NOUT * K * 2);

  cast_x_kernel<<<(M * (size_t)K) / 8 / 256, 256, 0, stream>>>(x, xb);
  w_fuse_kernel<<<((size_t)NOUT * K) / 8 / 256, 256, 0, stream>>>(mu_w, ls_w, ep_w, wb);
  bias_kernel<<<(NOUT + 255) / 256, 256, 0, stream>>>(mu_b, ls_b, ep_b, bias);

  dim3 grid(NOUT / 128, M / 128);
  gemm_bt_kernel<<<grid, 256, 0, stream>>>(xb, wb, bias, out);
}